// Round 10
// baseline (144.438 us; speedup 1.0000x reference)
//
#include <hip/hip_runtime.h>

#define SEQ 2048
#define NTOK 4096
#define DIM 1024
#define FQKV 3072
#define SC_Q (0.08838834764831843f * 1.4426950408889634f)  // 128^-.5 * log2e
#define SC_NORM 32.0f                  // sqrt(1024)

typedef short short8 __attribute__((ext_vector_type(8)));
typedef float f32x4 __attribute__((ext_vector_type(4)));
typedef unsigned short u16x4 __attribute__((ext_vector_type(4)));

__device__ __forceinline__ unsigned short f2bf(float f) {
    unsigned int u = __float_as_uint(f);
    u += 0x7fffu + ((u >> 16) & 1u);   // RNE
    return (unsigned short)(u >> 16);
}
__device__ __forceinline__ float bf2f(unsigned short b) {
    return __uint_as_float(((unsigned int)b) << 16);
}
__device__ __forceinline__ void gl_lds16(const void* g, void* l) {
    __builtin_amdgcn_global_load_lds((const __attribute__((address_space(1))) void*)g,
                                     (__attribute__((address_space(3))) void*)l, 16, 0, 0);
}

// ---------------------------------------------------------------------------
// prep: blocks [0,4096) = L2-norm per token; blocks [4096,8192) = weight conv
// ---------------------------------------------------------------------------
__global__ __launch_bounds__(256) void prep(const float* __restrict__ x,
                                            const float* __restrict__ gamma,
                                            unsigned short* __restrict__ xn,
                                            const float* __restrict__ wq,
                                            unsigned short* __restrict__ wqb,
                                            const float* __restrict__ wo,
                                            unsigned short* __restrict__ wob) {
    if (blockIdx.x < 4096) {
        int token = blockIdx.x;
        float4 v = ((const float4*)(x + (size_t)token * DIM))[threadIdx.x];
        float ss = v.x * v.x + v.y * v.y + v.z * v.z + v.w * v.w;
#pragma unroll
        for (int off = 32; off > 0; off >>= 1) ss += __shfl_down(ss, off);
        __shared__ float wsum[4];
        if ((threadIdx.x & 63) == 0) wsum[threadIdx.x >> 6] = ss;
        __syncthreads();
        float tot = wsum[0] + wsum[1] + wsum[2] + wsum[3];
        float sc = SC_NORM / fmaxf(sqrtf(tot), 1e-12f);
        float4 g = ((const float4*)gamma)[threadIdx.x];
        u16x4 o;
        o.x = f2bf(v.x * sc * g.x);
        o.y = f2bf(v.y * sc * g.y);
        o.z = f2bf(v.z * sc * g.z);
        o.w = f2bf(v.w * sc * g.w);
        ((u16x4*)(xn + (size_t)token * DIM))[threadIdx.x] = o;
    } else {
        int i = (blockIdx.x - 4096) * 256 + threadIdx.x;
        const float* w; unsigned short* o; int idx;
        if (i < 786432) { w = wq; o = wqb; idx = i; }
        else            { w = wo; o = wob; idx = i - 786432; }
        float4 v = ((const float4*)w)[idx];
        u16x4 r;
        r.x = f2bf(v.x); r.y = f2bf(v.y); r.z = f2bf(v.z); r.w = f2bf(v.w);
        ((u16x4*)o)[idx] = r;
    }
}

// ---------------------------------------------------------------------------
// bf16 GEMM NT (R8): TM x 128 tile, BK=64, single-buffer split-phase raw
// barriers, XCD-aware bijective swizzle.
// ---------------------------------------------------------------------------
template<int C_MODE, int TM>
__global__ __launch_bounds__(256) void gemm_bf16(const unsigned short* __restrict__ A,
                                                 const unsigned short* __restrict__ B,
                                                 void* __restrict__ Cv,
                                                 int M, int N, int K) {
    constexpr int MF = TM / 32;
    __shared__ unsigned short As[TM * 64];
    __shared__ unsigned short Bs[128 * 64];

    int lin = blockIdx.y * gridDim.x + blockIdx.x;
    int nwg = gridDim.x * gridDim.y;
    int w = (lin & 7) * (nwg >> 3) + (lin >> 3);
    int bx = w % gridDim.x, by = w / gridDim.x;

    const int bn = bx * 128, bm = by * TM;
    const int tid = threadIdx.x, lane = tid & 63, wv = tid >> 6;
    const int wr = wv >> 1, wc = wv & 1;
    const int l15 = lane & 15, g = lane >> 4;

    f32x4 acc[MF][4] = {};

    auto stage = [&](int k0) {
#pragma unroll
        for (int ia = 0; ia < TM / 32; ++ia) {
            int ci = ia * 256 + wv * 64 + lane;
            int row = ci >> 3, cc = ci & 7;
            int co = (cc ^ (row & 7)) << 3;
            gl_lds16(A + (size_t)(bm + row) * K + k0 + co, &As[(ia * 256 + wv * 64) * 8]);
        }
#pragma unroll
        for (int ib = 0; ib < 4; ++ib) {
            int ci = ib * 256 + wv * 64 + lane;
            int row = ci >> 3, cc = ci & 7;
            int co = (cc ^ (row & 7)) << 3;
            gl_lds16(B + (size_t)(bn + row) * K + k0 + co, &Bs[(ib * 256 + wv * 64) * 8]);
        }
    };

    stage(0);
    asm volatile("s_waitcnt vmcnt(0)\ns_barrier" ::: "memory");

    for (int k0 = 0; k0 < K; k0 += 64) {
        short8 af[2][MF], bf[2][4];
#pragma unroll
        for (int ks = 0; ks < 2; ++ks) {
#pragma unroll
            for (int f = 0; f < MF; ++f) {
                int ra = wr * (TM / 2) + f * 16 + l15;
                af[ks][f] = *(const short8*)&As[ra * 64 + (((ks * 4 + g) ^ (ra & 7)) << 3)];
            }
#pragma unroll
            for (int f = 0; f < 4; ++f) {
                int rb = wc * 64 + f * 16 + l15;
                bf[ks][f] = *(const short8*)&Bs[rb * 64 + (((ks * 4 + g) ^ (rb & 7)) << 3)];
            }
        }
        asm volatile("s_waitcnt lgkmcnt(0)\ns_barrier" ::: "memory");
        if (k0 + 64 < K) stage(k0 + 64);
#pragma unroll
        for (int ks = 0; ks < 2; ++ks)
#pragma unroll
            for (int i = 0; i < MF; ++i)
#pragma unroll
                for (int j = 0; j < 4; ++j)
                    acc[i][j] = __builtin_amdgcn_mfma_f32_16x16x32_bf16(af[ks][i], bf[ks][j], acc[i][j], 0, 0, 0);
        asm volatile("s_waitcnt vmcnt(0)\ns_barrier" ::: "memory");
    }

    if (C_MODE == 0) {
        float* C = (float*)Cv;
#pragma unroll
        for (int i = 0; i < MF; ++i)
#pragma unroll
            for (int j = 0; j < 4; ++j)
#pragma unroll
                for (int v = 0; v < 4; ++v) {
                    int row = bm + wr * (TM / 2) + i * 16 + g * 4 + v;
                    int col = bn + wc * 64 + j * 16 + l15;
                    C[(size_t)row * N + col] = acc[i][j][v];
                }
    } else {
        unsigned short* C = (unsigned short*)Cv;
        float s = (bn < 1024) ? SC_Q : 1.0f;
#pragma unroll
        for (int i = 0; i < MF; ++i)
#pragma unroll
            for (int j = 0; j < 4; ++j)
#pragma unroll
                for (int v = 0; v < 4; ++v) {
                    int row = bm + wr * (TM / 2) + i * 16 + g * 4 + v;
                    int col = bn + wc * 64 + j * 16 + l15;
                    C[(size_t)row * N + col] = f2bf(acc[i][j][v] * s);
                }
    }
}

// ---------------------------------------------------------------------------
// V transpose: qkv V-part [token][d] -> vt[(b*8+h)*128 + d][token]
// ---------------------------------------------------------------------------
__global__ __launch_bounds__(256) void transpose_v(const unsigned short* __restrict__ qkv,
                                                   unsigned short* __restrict__ vt) {
    __shared__ unsigned short T[64][72];
    const int t0 = blockIdx.x * 64, d0 = blockIdx.y * 64, bh = blockIdx.z;
    const int b = bh >> 3, h = bh & 7;
    const int tid = threadIdx.x;
#pragma unroll
    for (int p = 0; p < 2; ++p) {
        int r = p * 32 + (tid >> 3), c = tid & 7;
        *(short8*)&T[r][c * 8] =
            *(const short8*)(qkv + (size_t)(b * SEQ + t0 + r) * FQKV + 2048 + h * 128 + d0 + c * 8);
    }
    __syncthreads();
#pragma unroll
    for (int p = 0; p < 2; ++p) {
        int d = p * 32 + (tid >> 3), c = tid & 7;
        short8 v;
#pragma unroll
        for (int j = 0; j < 8; ++j) v[j] = (short)T[c * 8 + j][d];
        *(short8*)(vt + (size_t)(bh * 128 + d0 + d) * SEQ + t0 + c * 8) = v;
    }
}

// ---------------------------------------------------------------------------
// Flash attention, QB=128: 4 waves x 32 q-rows (2 q-frag sets e=0,1), KB=64.
// Each K/V fragment read from LDS feeds 2 MFMAs (halves LDS bytes/FLOP);
// merged q-blocks halve total KV-tile scans (528 -> 272 per b,h).
// K/V staged in opposite phases (R7), T13 defer-max per q-set.
// Split: qsb>=8 3-way, 4..7 2-way (bf16 partials, 512 slots in d_out),
// 0..3 unsplit. Longest pieces first.
// ---------------------------------------------------------------------------
__global__ __launch_bounds__(256) void attn_mfma(const unsigned short* __restrict__ qkv,
                                                 const unsigned short* __restrict__ vt,
                                                 unsigned short* __restrict__ ao,
                                                 unsigned short* __restrict__ po,
                                                 float* __restrict__ pml) {
    __shared__ unsigned short Ks[64 * 128];
    __shared__ unsigned short Vs[128 * 64];
    __shared__ unsigned short Ps[4][2][16 * 64];
    const int h = blockIdx.y, b = blockIdx.z;
    const int x = blockIdx.x;
    int qsb, s, nsp;
    if (x < 24)      { qsb = 15 - x / 3;               s = x % 3;  nsp = 3; }  // 15..8
    else if (x < 32) { int i = x - 24; qsb = 7 - (i >> 1); s = i & 1; nsp = 2; } // 7..4
    else             { qsb = 35 - x;                   s = 0;      nsp = 1; }  // 3..0
    const int T = 2 * qsb + 2;
    const int jb0 = (s * T) / nsp, jb1 = ((s + 1) * T) / nsp;
    const int split = (nsp > 1);
    const int slot = ((b * 8 + h) << 5) + x;           // x < 32 when split

    const int tid = threadIdx.x, lane = tid & 63, wv = tid >> 6;
    const int l15 = lane & 15, g = lane >> 4;
    const int q0 = qsb * 128;

    auto stageK = [&](int jb) {
#pragma unroll
        for (int inst = 0; inst < 4; ++inst) {
            int ci = inst * 256 + wv * 64 + lane;
            int rowk = ci >> 4, ck = ci & 15;
            gl_lds16(qkv + (size_t)(b * SEQ + jb * 64 + rowk) * FQKV + 1024 + h * 128
                         + ((ck ^ (rowk & 7)) << 3),
                     &Ks[(inst * 256 + wv * 64) * 8]);
        }
    };
    auto stageV = [&](int jb) {
#pragma unroll
        for (int inst = 0; inst < 4; ++inst) {
            int ci = inst * 256 + wv * 64 + lane;
            int rowv = ci >> 3, cv = ci & 7;
            gl_lds16(vt + (size_t)((b * 8 + h) * 128 + rowv) * SEQ + jb * 64
                        + ((cv ^ (rowv & 7)) << 3),
                     &Vs[(inst * 256 + wv * 64) * 8]);
        }
    };

    // Q fragments, 2 sets: qrow_e = q0 + wv*16 + e*64 + l15
    short8 qf[2][4];
#pragma unroll
    for (int e = 0; e < 2; ++e) {
        const unsigned short* qb = qkv + (size_t)(b * SEQ + q0 + wv * 16 + e * 64 + l15) * FQKV + h * 128;
#pragma unroll
        for (int ks = 0; ks < 4; ++ks) qf[e][ks] = *(const short8*)(qb + ks * 32 + g * 8);
    }

    float m_r[2] = {-1e30f, -1e30f}, l_r[2] = {0.f, 0.f};
    f32x4 o[2][8] = {};

    stageK(jb0);
    __syncthreads();

    for (int jb = jb0; jb < jb1; ++jb) {
        stageV(jb);

        // S^T = K Q^T for both q-sets: each K frag feeds 2 MFMAs
        f32x4 sv[2][4] = {};
        __builtin_amdgcn_s_setprio(1);
#pragma unroll
        for (int ks = 0; ks < 4; ++ks) {
#pragma unroll
            for (int fi = 0; fi < 4; ++fi) {
                int rk = fi * 16 + l15;
                short8 kf = *(const short8*)&Ks[rk * 128 + (((ks * 4 + g) ^ (rk & 7)) << 3)];
                sv[0][fi] = __builtin_amdgcn_mfma_f32_16x16x32_bf16(kf, qf[0][ks], sv[0][fi], 0, 0, 0);
                sv[1][fi] = __builtin_amdgcn_mfma_f32_16x16x32_bf16(kf, qf[1][ks], sv[1][fi], 0, 0, 0);
            }
        }
        __builtin_amdgcn_s_setprio(0);

        if (jb >= 2 * qsb) {   // diagonal region: causal mask per q-set
#pragma unroll
            for (int e = 0; e < 2; ++e) {
                int qrow = q0 + wv * 16 + e * 64 + l15;
#pragma unroll
                for (int fi = 0; fi < 4; ++fi)
#pragma unroll
                    for (int v = 0; v < 4; ++v) {
                        int kv = jb * 64 + fi * 16 + g * 4 + v;
                        if (kv > qrow) sv[e][fi][v] = -1e30f;
                    }
            }
        }

        // online softmax per q-set (row = l15-col of S^T; reduce over g)
#pragma unroll
        for (int e = 0; e < 2; ++e) {
            float mx = -1e30f;
#pragma unroll
            for (int fi = 0; fi < 4; ++fi)
                mx = fmaxf(mx, fmaxf(fmaxf(sv[e][fi][0], sv[e][fi][1]), fmaxf(sv[e][fi][2], sv[e][fi][3])));
            mx = fmaxf(mx, __shfl_xor(mx, 16));
            mx = fmaxf(mx, __shfl_xor(mx, 32));
            if (__any(mx - m_r[e] > 16.0f)) {
                float Mn = fmaxf(m_r[e], mx);
                float alpha = exp2f(m_r[e] - Mn);
                l_r[e] *= alpha;
                float av[4];
#pragma unroll
                for (int v = 0; v < 4; ++v) av[v] = __shfl(alpha, g * 4 + v);
#pragma unroll
                for (int fn = 0; fn < 8; ++fn) {
                    o[e][fn][0] *= av[0]; o[e][fn][1] *= av[1];
                    o[e][fn][2] *= av[2]; o[e][fn][3] *= av[3];
                }
                m_r[e] = Mn;
            }
            float ps = 0.f;
#pragma unroll
            for (int fi = 0; fi < 4; ++fi) {
#pragma unroll
                for (int p2 = 0; p2 < 2; ++p2) {
                    float e0 = exp2f(sv[e][fi][2 * p2] - m_r[e]);
                    float e1 = exp2f(sv[e][fi][2 * p2 + 1] - m_r[e]);
                    ps += e0 + e1;
                    unsigned short b0 = f2bf(e0), b1 = f2bf(e1);
                    int kv = fi * 16 + g * 4 + 2 * p2;
                    int addr = l15 * 64 + (((kv >> 3) ^ (l15 & 7)) << 3) + (kv & 7);
                    *(unsigned int*)&Ps[wv][e][addr] = (unsigned int)b0 | ((unsigned int)b1 << 16);
                }
            }
            ps += __shfl_xor(ps, 16);
            ps += __shfl_xor(ps, 32);
            l_r[e] += ps;
        }

        __syncthreads();                   // V(jb) landed; Ks reads done
        if (jb + 1 < jb1) stageK(jb + 1);  // flies under PV

        // O += P V : each V frag feeds 2 MFMAs
        __builtin_amdgcn_s_setprio(1);
#pragma unroll
        for (int ks = 0; ks < 2; ++ks) {
            short8 pa0 = *(const short8*)&Ps[wv][0][l15 * 64 + (((ks * 4 + g) ^ (l15 & 7)) << 3)];
            short8 pa1 = *(const short8*)&Ps[wv][1][l15 * 64 + (((ks * 4 + g) ^ (l15 & 7)) << 3)];
#pragma unroll
            for (int fn = 0; fn < 8; ++fn) {
                int rv = fn * 16 + l15;
                short8 vf = *(const short8*)&Vs[rv * 64 + (((ks * 4 + g) ^ (rv & 7)) << 3)];
                o[0][fn] = __builtin_amdgcn_mfma_f32_16x16x32_bf16(pa0, vf, o[0][fn], 0, 0, 0);
                o[1][fn] = __builtin_amdgcn_mfma_f32_16x16x32_bf16(pa1, vf, o[1][fn], 0, 0, 0);
            }
        }
        __builtin_amdgcn_s_setprio(0);

        __syncthreads();                   // K(jb+1) landed; Vs reads done
    }

    if (split) {
        unsigned short* od = po + (size_t)slot * 16384;   // bf16 partial O [128][128]
#pragma unroll
        for (int e = 0; e < 2; ++e)
#pragma unroll
            for (int fn = 0; fn < 8; ++fn)
#pragma unroll
                for (int v = 0; v < 4; ++v)
                    od[(wv * 16 + e * 64 + g * 4 + v) * 128 + fn * 16 + l15] = f2bf(o[e][fn][v]);
        if (g == 0) {
#pragma unroll
            for (int e = 0; e < 2; ++e) {
                pml[(size_t)slot * 256 + wv * 16 + e * 64 + l15] = m_r[e];
                pml[(size_t)slot * 256 + 128 + wv * 16 + e * 64 + l15] = l_r[e];
            }
        }
    } else {
#pragma unroll
        for (int e = 0; e < 2; ++e) {
            float lv[4];
#pragma unroll
            for (int v = 0; v < 4; ++v) lv[v] = 1.0f / __shfl(l_r[e], g * 4 + v);
#pragma unroll
            for (int fn = 0; fn < 8; ++fn)
#pragma unroll
                for (int v = 0; v < 4; ++v) {
                    int row = b * SEQ + q0 + wv * 16 + e * 64 + g * 4 + v;
                    ao[(size_t)row * DIM + h * 128 + fn * 16 + l15] = f2bf(o[e][fn][v] * lv[v]);
                }
        }
    }
}

// ---------------------------------------------------------------------------
// Combine n in {2,3} KV-split partials (128-row superblocks) -> bf16 output.
// grid (12, 8, 2): qsb = 4 + blockIdx.x. thread: row = tid>>1, 64-d half.
// ---------------------------------------------------------------------------
__global__ __launch_bounds__(256) void attn_combine(const unsigned short* __restrict__ po,
                                                    const float* __restrict__ pml,
                                                    unsigned short* __restrict__ ao) {
    const int qsb = 4 + blockIdx.x, h = blockIdx.y, b = blockIdx.z;
    int base, n;
    if (qsb >= 8) { base = (15 - qsb) * 3;      n = 3; }
    else          { base = 24 + (7 - qsb) * 2;  n = 2; }
    const int slot0 = ((b * 8 + h) << 5) + base;
    const int row = threadIdx.x >> 1, d0 = (threadIdx.x & 1) * 64;

    float M = -1e30f;
#pragma unroll
    for (int s2 = 0; s2 < 3; ++s2)
        if (s2 < n) M = fmaxf(M, pml[(size_t)(slot0 + s2) * 256 + row]);
    float denom = 0.f;
#pragma unroll
    for (int s2 = 0; s2 < 3; ++s2)
        if (s2 < n) denom += exp2f(pml[(size_t)(slot0 + s2) * 256 + row] - M)
                             * pml[(size_t)(slot0 + s2) * 256 + 128 + row];
    float inv = 1.0f / denom;

    float acc[64] = {};
#pragma unroll
    for (int s2 = 0; s2 < 3; ++s2)
        if (s2 < n) {
            float wgt = exp2f(pml[(size_t)(slot0 + s2) * 256 + row] - M) * inv;
            const unsigned short* ob = po + (size_t)(slot0 + s2) * 16384 + row * 128 + d0;
#pragma unroll
            for (int j = 0; j < 8; ++j) {
                short8 pv = *(const short8*)(ob + j * 8);
#pragma unroll
                for (int e = 0; e < 8; ++e)
                    acc[j * 8 + e] += wgt * bf2f((unsigned short)pv[e]);
            }
        }

    unsigned short* dst = ao + ((size_t)(b * SEQ + qsb * 128 + row)) * DIM + h * 128 + d0;
#pragma unroll
    for (int j = 0; j < 8; ++j) {
        short8 r;
#pragma unroll
        for (int e = 0; e < 8; ++e) r[e] = (short)f2bf(acc[j * 8 + e]);
        *(short8*)(dst + j * 8) = r;
    }
}

// ---------------------------------------------------------------------------
extern "C" void kernel_launch(void* const* d_in, const int* in_sizes, int n_in,
                              void* d_out, int out_size, void* d_ws, size_t ws_size,
                              hipStream_t stream) {
    const float* x     = (const float*)d_in[0];
    const float* gamma = (const float*)d_in[1];
    const float* w_qkv = (const float*)d_in[2];
    const float* w_out = (const float*)d_in[3];

    char* ws = (char*)d_ws;
    unsigned short* qkvb = (unsigned short*)ws;                   // 25165824 B  [4096][3072]
    unsigned short* vtb  = (unsigned short*)(ws + 25165824);      //  8388608 B  [16][128][2048]
    unsigned short* xnb  = (unsigned short*)(ws + 33554432);      //  8388608 B  [4096][1024]
    unsigned short* wqb  = (unsigned short*)(ws + 41943040);      //  6291456 B  [3072][1024]
    unsigned short* wob  = (unsigned short*)(ws + 48234496);      //  2097152 B  [1024][1024]
    unsigned short* aob  = (unsigned short*)(ws + 50331648);      //  8388608 B  [4096][1024]
    // pml overlaps wqb (dead after gemm1): 512 slots x 256 f32 = 512 KB
    float*          pml  = (float*)(ws + 41943040);
    unsigned short* po   = (unsigned short*)d_out;  // 512 slots x 128x128 bf16 = 16.78 MB

    prep<<<8192, 256, 0, stream>>>(x, gamma, xnb, w_qkv, wqb, w_out, wob);
    gemm_bf16<1, 128><<<dim3(24, 32), 256, 0, stream>>>(xnb, wqb, qkvb, NTOK, FQKV, DIM);
    transpose_v<<<dim3(32, 2, 16), 256, 0, stream>>>(qkvb, vtb);
    attn_mfma<<<dim3(36, 8, 2), 256, 0, stream>>>(qkvb, vtb, aob, po, pml);
    attn_combine<<<dim3(12, 8, 2), 256, 0, stream>>>(po, pml, aob);
    gemm_bf16<0, 64><<<dim3(8, 64), 256, 0, stream>>>(aob, wob, (float*)d_out, NTOK, DIM, DIM);
}

// Round 11
// 132.975 us; speedup vs baseline: 1.0862x; 1.0862x over previous
//
#include <hip/hip_runtime.h>

#define SEQ 2048
#define NTOK 4096
#define DIM 1024
#define FQKV 3072
#define SC_Q (0.08838834764831843f * 1.4426950408889634f)  // 128^-.5 * log2e
#define SC_NORM 32.0f                  // sqrt(1024)

typedef short short8 __attribute__((ext_vector_type(8)));
typedef float f32x4 __attribute__((ext_vector_type(4)));
typedef float f32x16 __attribute__((ext_vector_type(16)));
typedef unsigned short u16x4 __attribute__((ext_vector_type(4)));

__device__ __forceinline__ unsigned short f2bf(float f) {
    unsigned int u = __float_as_uint(f);
    u += 0x7fffu + ((u >> 16) & 1u);   // RNE
    return (unsigned short)(u >> 16);
}
__device__ __forceinline__ float bf2f(unsigned short b) {
    return __uint_as_float(((unsigned int)b) << 16);
}
__device__ __forceinline__ void gl_lds16(const void* g, void* l) {
    __builtin_amdgcn_global_load_lds((const __attribute__((address_space(1))) void*)g,
                                     (__attribute__((address_space(3))) void*)l, 16, 0, 0);
}

// ---------------------------------------------------------------------------
// prep: blocks [0,4096) = L2-norm per token; blocks [4096,8192) = weight conv
// ---------------------------------------------------------------------------
__global__ __launch_bounds__(256) void prep(const float* __restrict__ x,
                                            const float* __restrict__ gamma,
                                            unsigned short* __restrict__ xn,
                                            const float* __restrict__ wq,
                                            unsigned short* __restrict__ wqb,
                                            const float* __restrict__ wo,
                                            unsigned short* __restrict__ wob) {
    if (blockIdx.x < 4096) {
        int token = blockIdx.x;
        float4 v = ((const float4*)(x + (size_t)token * DIM))[threadIdx.x];
        float ss = v.x * v.x + v.y * v.y + v.z * v.z + v.w * v.w;
#pragma unroll
        for (int off = 32; off > 0; off >>= 1) ss += __shfl_down(ss, off);
        __shared__ float wsum[4];
        if ((threadIdx.x & 63) == 0) wsum[threadIdx.x >> 6] = ss;
        __syncthreads();
        float tot = wsum[0] + wsum[1] + wsum[2] + wsum[3];
        float sc = SC_NORM / fmaxf(sqrtf(tot), 1e-12f);
        float4 g = ((const float4*)gamma)[threadIdx.x];
        u16x4 o;
        o.x = f2bf(v.x * sc * g.x);
        o.y = f2bf(v.y * sc * g.y);
        o.z = f2bf(v.z * sc * g.z);
        o.w = f2bf(v.w * sc * g.w);
        ((u16x4*)(xn + (size_t)token * DIM))[threadIdx.x] = o;
    } else {
        int i = (blockIdx.x - 4096) * 256 + threadIdx.x;
        const float* w; unsigned short* o; int idx;
        if (i < 786432) { w = wq; o = wqb; idx = i; }
        else            { w = wo; o = wob; idx = i - 786432; }
        float4 v = ((const float4*)w)[idx];
        u16x4 r;
        r.x = f2bf(v.x); r.y = f2bf(v.y); r.z = f2bf(v.z); r.w = f2bf(v.w);
        ((u16x4*)o)[idx] = r;
    }
}

// ---------------------------------------------------------------------------
// bf16 GEMM NT (R8): TM x 128 tile, BK=64, single-buffer split-phase raw
// barriers, XCD-aware bijective swizzle.
// ---------------------------------------------------------------------------
template<int C_MODE, int TM>
__global__ __launch_bounds__(256) void gemm_bf16(const unsigned short* __restrict__ A,
                                                 const unsigned short* __restrict__ B,
                                                 void* __restrict__ Cv,
                                                 int M, int N, int K) {
    constexpr int MF = TM / 32;
    __shared__ unsigned short As[TM * 64];
    __shared__ unsigned short Bs[128 * 64];

    int lin = blockIdx.y * gridDim.x + blockIdx.x;
    int nwg = gridDim.x * gridDim.y;
    int w = (lin & 7) * (nwg >> 3) + (lin >> 3);
    int bx = w % gridDim.x, by = w / gridDim.x;

    const int bn = bx * 128, bm = by * TM;
    const int tid = threadIdx.x, lane = tid & 63, wv = tid >> 6;
    const int wr = wv >> 1, wc = wv & 1;
    const int l15 = lane & 15, g = lane >> 4;

    f32x4 acc[MF][4] = {};

    auto stage = [&](int k0) {
#pragma unroll
        for (int ia = 0; ia < TM / 32; ++ia) {
            int ci = ia * 256 + wv * 64 + lane;
            int row = ci >> 3, cc = ci & 7;
            int co = (cc ^ (row & 7)) << 3;
            gl_lds16(A + (size_t)(bm + row) * K + k0 + co, &As[(ia * 256 + wv * 64) * 8]);
        }
#pragma unroll
        for (int ib = 0; ib < 4; ++ib) {
            int ci = ib * 256 + wv * 64 + lane;
            int row = ci >> 3, cc = ci & 7;
            int co = (cc ^ (row & 7)) << 3;
            gl_lds16(B + (size_t)(bn + row) * K + k0 + co, &Bs[(ib * 256 + wv * 64) * 8]);
        }
    };

    stage(0);
    asm volatile("s_waitcnt vmcnt(0)\ns_barrier" ::: "memory");

    for (int k0 = 0; k0 < K; k0 += 64) {
        short8 af[2][MF], bf[2][4];
#pragma unroll
        for (int ks = 0; ks < 2; ++ks) {
#pragma unroll
            for (int f = 0; f < MF; ++f) {
                int ra = wr * (TM / 2) + f * 16 + l15;
                af[ks][f] = *(const short8*)&As[ra * 64 + (((ks * 4 + g) ^ (ra & 7)) << 3)];
            }
#pragma unroll
            for (int f = 0; f < 4; ++f) {
                int rb = wc * 64 + f * 16 + l15;
                bf[ks][f] = *(const short8*)&Bs[rb * 64 + (((ks * 4 + g) ^ (rb & 7)) << 3)];
            }
        }
        asm volatile("s_waitcnt lgkmcnt(0)\ns_barrier" ::: "memory");
        if (k0 + 64 < K) stage(k0 + 64);
#pragma unroll
        for (int ks = 0; ks < 2; ++ks)
#pragma unroll
            for (int i = 0; i < MF; ++i)
#pragma unroll
                for (int j = 0; j < 4; ++j)
                    acc[i][j] = __builtin_amdgcn_mfma_f32_16x16x32_bf16(af[ks][i], bf[ks][j], acc[i][j], 0, 0, 0);
        asm volatile("s_waitcnt vmcnt(0)\ns_barrier" ::: "memory");
    }

    if (C_MODE == 0) {
        float* C = (float*)Cv;
#pragma unroll
        for (int i = 0; i < MF; ++i)
#pragma unroll
            for (int j = 0; j < 4; ++j)
#pragma unroll
                for (int v = 0; v < 4; ++v) {
                    int row = bm + wr * (TM / 2) + i * 16 + g * 4 + v;
                    int col = bn + wc * 64 + j * 16 + l15;
                    C[(size_t)row * N + col] = acc[i][j][v];
                }
    } else {
        unsigned short* C = (unsigned short*)Cv;
        float s = (bn < 1024) ? SC_Q : 1.0f;
#pragma unroll
        for (int i = 0; i < MF; ++i)
#pragma unroll
            for (int j = 0; j < 4; ++j)
#pragma unroll
                for (int v = 0; v < 4; ++v) {
                    int row = bm + wr * (TM / 2) + i * 16 + g * 4 + v;
                    int col = bn + wc * 64 + j * 16 + l15;
                    C[(size_t)row * N + col] = f2bf(acc[i][j][v] * s);
                }
    }
}

// ---------------------------------------------------------------------------
// V transpose: qkv V-part [token][d] -> vt[(b*8+h)*128 + d][token]
// ---------------------------------------------------------------------------
__global__ __launch_bounds__(256) void transpose_v(const unsigned short* __restrict__ qkv,
                                                   unsigned short* __restrict__ vt) {
    __shared__ unsigned short T[64][72];
    const int t0 = blockIdx.x * 64, d0 = blockIdx.y * 64, bh = blockIdx.z;
    const int b = bh >> 3, h = bh & 7;
    const int tid = threadIdx.x;
#pragma unroll
    for (int p = 0; p < 2; ++p) {
        int r = p * 32 + (tid >> 3), c = tid & 7;
        *(short8*)&T[r][c * 8] =
            *(const short8*)(qkv + (size_t)(b * SEQ + t0 + r) * FQKV + 2048 + h * 128 + d0 + c * 8);
    }
    __syncthreads();
#pragma unroll
    for (int p = 0; p < 2; ++p) {
        int d = p * 32 + (tid >> 3), c = tid & 7;
        short8 v;
#pragma unroll
        for (int j = 0; j < 8; ++j) v[j] = (short)T[c * 8 + j][d];
        *(short8*)(vt + (size_t)(bh * 128 + d0 + d) * SEQ + t0 + c * 8) = v;
    }
}

// ---------------------------------------------------------------------------
// Flash attention, 32x32x16 MFMA. 2 waves x 32 q-rows (QB=64), KB=64.
// Swapped QK^T: S^T[kv][q] -> lane (col=lane&31) owns its q-row entirely:
// softmax max/sum = in-register reduce + 1 shfl_xor(32); rescale/normalize
// per-lane scalar (no broadcasts). P packed via v_cvt_pk_bf16_f32 into a
// 2KB/wave XOR-swizzled LDS buffer, read back as PV's B-fragment.
// K/V staged opposite phases (R7). T13 defer-max. R9 balanced split
// (73 blocks/(b,h), bf16 partials in d_out).
// ---------------------------------------------------------------------------
__global__ __launch_bounds__(128) void attn_mfma(const unsigned short* __restrict__ qkv,
                                                 const unsigned short* __restrict__ vt,
                                                 unsigned short* __restrict__ ao,
                                                 unsigned short* __restrict__ po,
                                                 float* __restrict__ pml) {
    __shared__ unsigned short Ks[64 * 128];
    __shared__ unsigned short Vs[128 * 64];
    __shared__ unsigned int Ps[2][32 * 32];   // per wave: 32 q x 32 u32 (64 kv bf16)
    const int h = blockIdx.y, b = blockIdx.z;
    const int x = blockIdx.x;
    int qblk, s, nsp;
    if (x < 30)      { qblk = 27 - x / 3;               s = x % 3;  nsp = 3; }  // 27..18
    else if (x < 46) { int i = x - 30; qblk = 31 - (i >> 2); s = i & 3; nsp = 4; } // 31..28
    else if (x < 64) { int i = x - 46; qblk = 17 - (i >> 1); s = i & 1; nsp = 2; } // 17..9
    else             { qblk = 72 - x;                   s = 0;      nsp = 1; }  // 8..0
    const int T = qblk + 1;
    const int jb0 = (s * T) / nsp, jb1 = ((s + 1) * T) / nsp;
    const int split = (nsp > 1);
    const int slot = ((b * 8 + h) << 6) + x;   // valid when split (x<64)

    const int tid = threadIdx.x, lane = tid & 63, wv = tid >> 6;   // wv in {0,1}
    const int q = lane & 31, hi = lane >> 5;
    const int q0 = qblk * 64;
    const int qrow = q0 + wv * 32 + q;

    auto stageK = [&](int jb) {
#pragma unroll
        for (int inst = 0; inst < 8; ++inst) {
            int ci = inst * 128 + tid;
            int rowk = ci >> 4, ck = ci & 15;
            gl_lds16(qkv + (size_t)(b * SEQ + jb * 64 + rowk) * FQKV + 1024 + h * 128
                         + ((ck ^ (rowk & 7)) << 3),
                     &Ks[ci * 8]);
        }
    };
    auto stageV = [&](int jb) {
#pragma unroll
        for (int inst = 0; inst < 8; ++inst) {
            int ci = inst * 128 + tid;
            int rowv = ci >> 3, cv = ci & 7;
            gl_lds16(vt + (size_t)((b * 8 + h) * 128 + rowv) * SEQ + jb * 64
                        + ((cv ^ (rowv & 7)) << 3),
                     &Vs[ci * 8]);
        }
    };

    // Q fragments (B-operand, 32x32x16): lane (q, hi): k = ks*16 + hi*8 + j
    short8 qf[8];
    {
        const unsigned short* qb = qkv + (size_t)(b * SEQ + qrow) * FQKV + h * 128;
#pragma unroll
        for (int ks = 0; ks < 8; ++ks) qf[ks] = *(const short8*)(qb + ks * 16 + hi * 8);
    }

    float m_r = -1e30f, l_r = 0.f;
    f32x16 o[4] = {};   // O^T[d][q]: fd blocks of 32 d

    stageK(jb0);
    __syncthreads();

    for (int jb = jb0; jb < jb1; ++jb) {
        stageV(jb);                         // flies under QK^T + softmax

        // S^T = K Q^T : A = K[fi*32+q][k], B = Q
        f32x16 sv[2] = {};
        __builtin_amdgcn_s_setprio(1);
#pragma unroll
        for (int ks = 0; ks < 8; ++ks) {
#pragma unroll
            for (int fi = 0; fi < 2; ++fi) {
                int rk = fi * 32 + q;
                short8 kf = *(const short8*)&Ks[rk * 128 + (((ks * 2 + hi) ^ (rk & 7)) << 3)];
                sv[fi] = __builtin_amdgcn_mfma_f32_32x32x16_bf16(kf, qf[ks], sv[fi], 0, 0, 0);
            }
        }
        __builtin_amdgcn_s_setprio(0);

        if (jb == qblk) {   // diagonal tile: causal mask
#pragma unroll
            for (int fi = 0; fi < 2; ++fi)
#pragma unroll
                for (int r = 0; r < 16; ++r) {
                    int kv = jb * 64 + fi * 32 + (r & 3) + 8 * (r >> 2) + 4 * hi;
                    if (kv > qrow) sv[fi][r] = -1e30f;
                }
        }

        // softmax: lane owns q-row; 32 in-register + 1 shfl_xor(32)
        float mx = -1e30f;
#pragma unroll
        for (int fi = 0; fi < 2; ++fi)
#pragma unroll
            for (int r = 0; r < 16; ++r) mx = fmaxf(mx, sv[fi][r]);
        mx = fmaxf(mx, __shfl_xor(mx, 32));
        if (__any(mx - m_r > 16.0f)) {      // T13 defer-max
            float Mn = fmaxf(m_r, mx);
            float alpha = exp2f(m_r - Mn);
            l_r *= alpha;
#pragma unroll
            for (int fd = 0; fd < 4; ++fd)
#pragma unroll
                for (int r = 0; r < 16; ++r) o[fd][r] *= alpha;
            m_r = Mn;
        }

        float ps = 0.f;
#pragma unroll
        for (int fi = 0; fi < 2; ++fi) {
#pragma unroll
            for (int rp = 0; rp < 8; ++rp) {
                float e0 = exp2f(sv[fi][2 * rp] - m_r);
                float e1 = exp2f(sv[fi][2 * rp + 1] - m_r);
                ps += e0 + e1;
                unsigned int pk;
                asm("v_cvt_pk_bf16_f32 %0, %1, %2" : "=v"(pk) : "v"(e0), "v"(e1));
                int kvp = (rp & 1) + ((rp >> 1) << 2) + 2 * hi + fi * 16;  // kv/2
                Ps[wv][q * 32 + (kvp ^ ((q & 7) << 2))] = pk;
            }
        }
        ps += __shfl_xor(ps, 32);
        l_r += ps;

        __syncthreads();                    // V(jb) landed; Ks reads done; Ps drained
        if (jb + 1 < jb1) stageK(jb + 1);   // flies under PV

        // O^T += V^T P : A = Vt[fd*32+q][kv], B = P[q][kv] from Ps
        __builtin_amdgcn_s_setprio(1);
#pragma unroll
        for (int c = 0; c < 4; ++c) {
            short8 pb = *(const short8*)((const unsigned short*)
                            &Ps[wv][q * 32 + (((c * 8 + hi * 4)) ^ ((q & 7) << 2))]);
#pragma unroll
            for (int fd = 0; fd < 4; ++fd) {
                int rv = fd * 32 + q;
                short8 vf = *(const short8*)&Vs[rv * 64 + (((c * 2 + hi) ^ (rv & 7)) << 3)];
                o[fd] = __builtin_amdgcn_mfma_f32_32x32x16_bf16(vf, pb, o[fd], 0, 0, 0);
            }
        }
        __builtin_amdgcn_s_setprio(0);

        __syncthreads();                    // K(jb+1) landed; Vs reads done
    }

    // epilogue: per-lane scalar normalize (lane owns q-row)
    if (split) {
        unsigned short* od = po + (size_t)slot * 8192;   // [64][128] bf16, unnormalized
#pragma unroll
        for (int fd = 0; fd < 4; ++fd)
#pragma unroll
            for (int rp = 0; rp < 8; ++rp) {
                float e0 = o[fd][2 * rp], e1 = o[fd][2 * rp + 1];
                unsigned int pk;
                asm("v_cvt_pk_bf16_f32 %0, %1, %2" : "=v"(pk) : "v"(e0), "v"(e1));
                int d = fd * 32 + ((2 * rp) & 3) + 8 * (rp >> 1) + 4 * hi;
                *(unsigned int*)(od + (wv * 32 + q) * 128 + d) = pk;
            }
        if (hi == 0) {
            pml[(size_t)slot * 128 + wv * 32 + q] = m_r;
            pml[(size_t)slot * 128 + 64 + wv * 32 + q] = l_r;
        }
    } else {
        float inv = 1.0f / l_r;
        unsigned short* dst = ao + (size_t)(b * SEQ + qrow) * DIM + h * 128;
#pragma unroll
        for (int fd = 0; fd < 4; ++fd)
#pragma unroll
            for (int rp = 0; rp < 8; ++rp) {
                float e0 = o[fd][2 * rp] * inv, e1 = o[fd][2 * rp + 1] * inv;
                unsigned int pk;
                asm("v_cvt_pk_bf16_f32 %0, %1, %2" : "=v"(pk) : "v"(e0), "v"(e1));
                int d = fd * 32 + ((2 * rp) & 3) + 8 * (rp >> 1) + 4 * hi;
                *(unsigned int*)(dst + d) = pk;
            }
    }
}

// ---------------------------------------------------------------------------
// Combine n in {2,3,4} KV-split partials -> normalized bf16 output (R9).
// grid (23, 8, 2): qblk = 9 + blockIdx.x. thread: row=tid>>2, 32-d chunk.
// ---------------------------------------------------------------------------
__global__ __launch_bounds__(256) void attn_combine(const unsigned short* __restrict__ po,
                                                    const float* __restrict__ pml,
                                                    unsigned short* __restrict__ ao) {
    const int qblk = 9 + blockIdx.x, h = blockIdx.y, b = blockIdx.z;
    int base, n;
    if (qblk >= 28)      { base = 30 + (31 - qblk) * 4; n = 4; }
    else if (qblk >= 18) { base = (27 - qblk) * 3;      n = 3; }
    else                 { base = 46 + (17 - qblk) * 2; n = 2; }
    const int slot0 = ((b * 8 + h) << 6) + base;
    const int row = threadIdx.x >> 2, dp = threadIdx.x & 3;

    float M = -1e30f;
#pragma unroll
    for (int s2 = 0; s2 < 4; ++s2)
        if (s2 < n) M = fmaxf(M, pml[(size_t)(slot0 + s2) * 128 + row]);
    float denom = 0.f;
#pragma unroll
    for (int s2 = 0; s2 < 4; ++s2)
        if (s2 < n) denom += exp2f(pml[(size_t)(slot0 + s2) * 128 + row] - M)
                             * pml[(size_t)(slot0 + s2) * 128 + 64 + row];
    float inv = 1.0f / denom;

    float acc[32] = {};
#pragma unroll
    for (int s2 = 0; s2 < 4; ++s2)
        if (s2 < n) {
            float wgt = exp2f(pml[(size_t)(slot0 + s2) * 128 + row] - M) * inv;
            const unsigned short* ob = po + (size_t)(slot0 + s2) * 8192 + row * 128 + dp * 32;
#pragma unroll
            for (int j = 0; j < 4; ++j) {
                short8 pv = *(const short8*)(ob + j * 8);
#pragma unroll
                for (int e = 0; e < 8; ++e)
                    acc[j * 8 + e] += wgt * bf2f((unsigned short)pv[e]);
            }
        }

    unsigned short* dst = ao + ((size_t)(b * SEQ + qblk * 64 + row)) * DIM + h * 128 + dp * 32;
#pragma unroll
    for (int j = 0; j < 4; ++j) {
        short8 r;
#pragma unroll
        for (int e = 0; e < 8; ++e) r[e] = (short)f2bf(acc[j * 8 + e]);
        *(short8*)(dst + j * 8) = r;
    }
}

// ---------------------------------------------------------------------------
extern "C" void kernel_launch(void* const* d_in, const int* in_sizes, int n_in,
                              void* d_out, int out_size, void* d_ws, size_t ws_size,
                              hipStream_t stream) {
    const float* x     = (const float*)d_in[0];
    const float* gamma = (const float*)d_in[1];
    const float* w_qkv = (const float*)d_in[2];
    const float* w_out = (const float*)d_in[3];

    char* ws = (char*)d_ws;
    unsigned short* qkvb = (unsigned short*)ws;                   // 25165824 B  [4096][3072]
    unsigned short* vtb  = (unsigned short*)(ws + 25165824);      //  8388608 B  [16][128][2048]
    unsigned short* xnb  = (unsigned short*)(ws + 33554432);      //  8388608 B  [4096][1024]
    unsigned short* wqb  = (unsigned short*)(ws + 41943040);      //  6291456 B  [3072][1024]
    unsigned short* wob  = (unsigned short*)(ws + 48234496);      //  2097152 B  [1024][1024]
    unsigned short* aob  = (unsigned short*)(ws + 50331648);      //  8388608 B  [4096][1024]
    // pml overlaps wqb (dead after gemm1): 1024 slots x 128 f32 = 512 KB
    float*          pml  = (float*)(ws + 41943040);
    unsigned short* po   = (unsigned short*)d_out;  // 1024 slots x 64x128 bf16 = 16.78 MB

    prep<<<8192, 256, 0, stream>>>(x, gamma, xnb, w_qkv, wqb, w_out, wob);
    gemm_bf16<1, 128><<<dim3(24, 32), 256, 0, stream>>>(xnb, wqb, qkvb, NTOK, FQKV, DIM);
    transpose_v<<<dim3(32, 2, 16), 256, 0, stream>>>(qkvb, vtb);
    attn_mfma<<<dim3(73, 8, 2), 128, 0, stream>>>(qkvb, vtb, aob, po, pml);
    attn_combine<<<dim3(23, 8, 2), 256, 0, stream>>>(po, pml, aob);
    gemm_bf16<0, 64><<<dim3(8, 64), 256, 0, stream>>>(aob, wob, (float*)d_out, NTOK, DIM, DIM);
}